// Round 1
// baseline (5388.560 us; speedup 1.0000x reference)
//
#include <hip/hip_runtime.h>
#include <hip/hip_bf16.h>
#include <math.h>

#define BB 128
#define NN 256
#define HH 512
#define T_STEPS 32

__device__ __forceinline__ float fast_tanh(float x) {
    float e = __expf(2.0f * x);
    return 1.0f - 2.0f / (1.0f + e);
}
__device__ __forceinline__ float fast_sigmoid(float x) {
    return 1.0f / (1.0f + __expf(-x));
}

__global__ void init_kernel(float* __restrict__ hT0, float* __restrict__ xT,
                            int* __restrict__ mask) {
    int tid = blockIdx.x * blockDim.x + threadIdx.x;
    int nt = gridDim.x * blockDim.x;
    for (int i = tid; i < HH * BB; i += nt) { hT0[i] = 0.f; xT[i] = 0.f; }
    for (int i = tid; i < BB * NN; i += nt) mask[i] = 0;
}

// W1e[i*H + k] = dot(enc[i, :], W1[k, :])   i in [0, B*N), k in [0, H)
__global__ __launch_bounds__(256) void w1e_gemm(const float* __restrict__ enc,
                                                const float* __restrict__ W1,
                                                float* __restrict__ W1e) {
    int tid = threadIdx.x;
    int ti = tid >> 4, tk = tid & 15;
    int i0 = blockIdx.x * 32 + ti * 2;
    int k0 = blockIdx.y * 64 + tk * 4;
    const float* a0 = enc + (size_t)i0 * HH;
    const float* a1 = a0 + HH;
    const float* w0 = W1 + (size_t)k0 * HH;
    float acc0[4] = {0.f, 0.f, 0.f, 0.f};
    float acc1[4] = {0.f, 0.f, 0.f, 0.f};
    for (int j = 0; j < HH; j += 4) {
        float4 av0 = *(const float4*)(a0 + j);
        float4 av1 = *(const float4*)(a1 + j);
#pragma unroll
        for (int c = 0; c < 4; c++) {
            float4 wv = *(const float4*)(w0 + c * HH + j);
            acc0[c] += av0.x * wv.x + av0.y * wv.y + av0.z * wv.z + av0.w * wv.w;
            acc1[c] += av1.x * wv.x + av1.y * wv.y + av1.z * wv.z + av1.w * wv.w;
        }
    }
    float4 r0 = make_float4(acc0[0], acc0[1], acc0[2], acc0[3]);
    float4 r1 = make_float4(acc1[0], acc1[1], acc1[2], acc1[3]);
    *(float4*)(W1e + (size_t)i0 * HH + k0) = r0;
    *(float4*)(W1e + (size_t)(i0 + 1) * HH + k0) = r1;
}

// block covers 2 k-values x all 128 b. hT layout: hT[k*B + b]
__global__ __launch_bounds__(256) void gru_kernel(
    const float* __restrict__ hT_cur, float* __restrict__ hT_next,
    const float* __restrict__ xT,
    const float* __restrict__ w_ih, const float* __restrict__ w_hh,
    const float* __restrict__ b_ih, const float* __restrict__ b_hh) {
    __shared__ float lds_w[12 * HH];
    int tid = threadIdx.x;
    int k0 = blockIdx.x * 2;
    for (int u = tid; u < 12 * HH; u += 256) {
        int r = u >> 9, j = u & (HH - 1);
        int s = r / 6, rem = r % 6;
        int m = rem / 3, g = rem % 3;
        int row = g * HH + k0 + s;
        const float* src = m ? w_hh : w_ih;
        lds_w[u] = src[(size_t)row * HH + j];
    }
    __syncthreads();
    int b = tid & 127, s = tid >> 7;
    int k = k0 + s;
    const float* wp = lds_w + s * 6 * HH;
    float a_ir = 0.f, a_iz = 0.f, a_in = 0.f, a_hr = 0.f, a_hz = 0.f, a_hn = 0.f;
#pragma unroll 4
    for (int j = 0; j < HH; j++) {
        float xv = xT[j * BB + b];
        float hv = hT_cur[j * BB + b];
        a_ir += xv * wp[j];
        a_iz += xv * wp[HH + j];
        a_in += xv * wp[2 * HH + j];
        a_hr += hv * wp[3 * HH + j];
        a_hz += hv * wp[4 * HH + j];
        a_hn += hv * wp[5 * HH + j];
    }
    float r = fast_sigmoid(a_ir + b_ih[k] + a_hr + b_hh[k]);
    float z = fast_sigmoid(a_iz + b_ih[HH + k] + a_hz + b_hh[HH + k]);
    float n = fast_tanh(a_in + b_ih[2 * HH + k] + r * (a_hn + b_hh[2 * HH + k]));
    float hold = hT_cur[k * BB + b];
    hT_next[k * BB + b] = (1.0f - z) * n + z * hold;
}

// W2h[b*H + k] = dot(W2[k,:], h_new[b,:]);  2 k per block x 128 b
__global__ __launch_bounds__(256) void w2h_kernel(
    const float* __restrict__ hT, const float* __restrict__ W2,
    float* __restrict__ W2h) {
    __shared__ float w2l[2 * HH];
    int tid = threadIdx.x;
    int k0 = blockIdx.x * 2;
    for (int u = tid; u < 2 * HH; u += 256)
        w2l[u] = W2[(size_t)(k0 + (u >> 9)) * HH + (u & (HH - 1))];
    __syncthreads();
    int b = tid & 127, s = tid >> 7;
    const float* wl = w2l + s * HH;
    float acc = 0.f;
#pragma unroll 4
    for (int j = 0; j < HH; j++)
        acc += hT[j * BB + b] * wl[j];
    W2h[b * HH + k0 + s] = acc;
}

// one block per batch row b; 1024 threads
__global__ __launch_bounds__(1024) void attn_kernel(
    const float* __restrict__ W1e, const float* __restrict__ W2h,
    const float* __restrict__ v, int* __restrict__ mask,
    const float* __restrict__ enc, float* __restrict__ xT,
    float* __restrict__ out, int t) {
    __shared__ float w2l[HH];
    __shared__ float vl[HH];
    __shared__ float ul[NN];
    __shared__ float redv[16];
    __shared__ int redi[16];
    __shared__ float s_m, s_inv;
    __shared__ int s_idx;
    int b = blockIdx.x, tid = threadIdx.x;
    if (tid < HH) w2l[tid] = W2h[b * HH + tid];
    else vl[tid - HH] = v[tid - HH];
    __syncthreads();

    // u[b, n] = sum_k tanh(W1e[b,n,k] + W2h[b,k]) * v[k]
    int n = tid >> 2, q = tid & 3;
    const float* Wp = W1e + ((size_t)b * NN + n) * HH + q * 128;
    const float* w2p = w2l + q * 128;
    const float* vp = vl + q * 128;
    float part = 0.f;
#pragma unroll 4
    for (int jj = 0; jj < 128; jj += 4) {
        float4 wv = *(const float4*)(Wp + jj);
        part += fast_tanh(wv.x + w2p[jj]) * vp[jj];
        part += fast_tanh(wv.y + w2p[jj + 1]) * vp[jj + 1];
        part += fast_tanh(wv.z + w2p[jj + 2]) * vp[jj + 2];
        part += fast_tanh(wv.w + w2p[jj + 3]) * vp[jj + 3];
    }
    part += __shfl_xor(part, 1);
    part += __shfl_xor(part, 2);
    if (q == 0) ul[n] = part;
    __syncthreads();

    // masked value + first-index argmax
    float val = -3.0e38f;
    int bi = 1 << 30;
    if (tid < NN) {
        val = mask[b * NN + tid] ? -1.0e9f : ul[tid];
        bi = tid;
    }
    float bv = val;
    int wid = tid >> 6, lane = tid & 63;
    for (int off = 32; off > 0; off >>= 1) {
        float ov = __shfl_down(bv, off);
        int oi = __shfl_down(bi, off);
        if (ov > bv || (ov == bv && oi < bi)) { bv = ov; bi = oi; }
    }
    if (lane == 0) { redv[wid] = bv; redi[wid] = bi; }
    __syncthreads();
    if (tid == 0) {
        float m = redv[0]; int mi = redi[0];
        for (int w = 1; w < 16; w++) {
            if (redv[w] > m || (redv[w] == m && redi[w] < mi)) { m = redv[w]; mi = redi[w]; }
        }
        s_m = m; s_idx = mi;
    }
    __syncthreads();

    // softmax denominator
    float e = 0.f;
    if (tid < NN) e = expf(val - s_m);
    float sv = e;
    for (int off = 32; off > 0; off >>= 1) sv += __shfl_down(sv, off);
    if (lane == 0) redv[wid] = sv;
    __syncthreads();
    if (tid == 0) {
        float ssum = 0.f;
        for (int w = 0; w < 16; w++) ssum += redv[w];
        s_inv = 1.0f / ssum;
    }
    __syncthreads();

    // entropy
    float inv = s_inv;
    float term = 0.f;
    if (tid < NN) {
        float p = e * inv;
        term = p * logf(p + 1e-9f);
    }
    float tv = term;
    for (int off = 32; off > 0; off >>= 1) tv += __shfl_down(tv, off);
    if (lane == 0) redv[wid] = tv;
    __syncthreads();

    int idx = s_idx;
    if (tid == 0) {
        float ent = 0.f;
        for (int w = 0; w < 16; w++) ent += redv[w];
        out[b * T_STEPS + t] = (float)idx;
        out[BB * T_STEPS + b * T_STEPS + t] = logf(inv + 1e-9f);
        out[2 * BB * T_STEPS + b * T_STEPS + t] = -ent;
        mask[b * NN + idx] = 1;
    }
    __syncthreads();
    // gather prev_embed for next step into xT (transposed)
    if (tid < HH) xT[tid * BB + b] = enc[((size_t)b * NN + idx) * HH + tid];
}

extern "C" void kernel_launch(void* const* d_in, const int* in_sizes, int n_in,
                              void* d_out, int out_size, void* d_ws, size_t ws_size,
                              hipStream_t stream) {
    const float* enc  = (const float*)d_in[0];
    const float* w_ih = (const float*)d_in[1];
    const float* w_hh = (const float*)d_in[2];
    const float* b_ih = (const float*)d_in[3];
    const float* b_hh = (const float*)d_in[4];
    const float* W1   = (const float*)d_in[5];
    const float* W2   = (const float*)d_in[6];
    const float* v    = (const float*)d_in[7];
    float* out = (float*)d_out;

    float* ws = (float*)d_ws;
    float* W1e = ws;                       // 16777216 floats (64 MB)
    float* hT0 = W1e + (size_t)BB * NN * HH;  // 65536
    float* hT1 = hT0 + HH * BB;            // 65536
    float* xT  = hT1 + HH * BB;            // 65536
    float* W2h = xT + HH * BB;             // 65536
    int*   mask = (int*)(W2h + HH * BB);   // 32768 ints

    init_kernel<<<64, 256, 0, stream>>>(hT0, xT, mask);
    w1e_gemm<<<dim3((BB * NN) / 32, HH / 64), 256, 0, stream>>>(enc, W1, W1e);

    for (int t = 0; t < T_STEPS; t++) {
        float* hc = (t & 1) ? hT1 : hT0;
        float* hn = (t & 1) ? hT0 : hT1;
        gru_kernel<<<HH / 2, 256, 0, stream>>>(hc, hn, xT, w_ih, w_hh, b_ih, b_hh);
        w2h_kernel<<<HH / 2, 256, 0, stream>>>(hn, W2, W2h);
        attn_kernel<<<BB, 1024, 0, stream>>>(W1e, W2h, v, mask, enc, xT, out, t);
    }
}

// Round 2
// 4182.062 us; speedup vs baseline: 1.2885x; 1.2885x over previous
//
#include <hip/hip_runtime.h>
#include <hip/hip_bf16.h>
#include <math.h>

#define BB 128
#define NN 256
#define HH 512
#define T_STEPS 32

__device__ __forceinline__ float fast_tanh(float x) {
    float e = __expf(2.0f * x);
    return 1.0f - 2.0f / (1.0f + e);
}
__device__ __forceinline__ float fast_sigmoid(float x) {
    return 1.0f / (1.0f + __expf(-x));
}

__global__ void init_kernel(float* __restrict__ hT0, float* __restrict__ xT,
                            int* __restrict__ mask) {
    int tid = blockIdx.x * blockDim.x + threadIdx.x;
    int nt = gridDim.x * blockDim.x;
    for (int i = tid; i < HH * BB; i += nt) { hT0[i] = 0.f; xT[i] = 0.f; }
    for (int i = tid; i < BB * NN; i += nt) mask[i] = 0;
}

// C[i,k] = dot(enc[i,:], W1[k,:])  — 32768x512x512 fp32 GEMM, LDS-tiled.
// 64x64 tile, BK=32, 256 threads, 4x4 acc per thread.
__global__ __launch_bounds__(256) void w1e_gemm(const float* __restrict__ enc,
                                                const float* __restrict__ W1,
                                                float* __restrict__ W1e) {
    __shared__ float As[32][64];
    __shared__ float Bs[32][64];
    int tid = threadIdx.x;
    int i0 = blockIdx.x * 64;
    int k0 = blockIdx.y * 64;
    int tx = tid & 15, ty = tid >> 4;   // tx: i-quad, ty: k-quad
    int srow = tid >> 3, sq = tid & 7;  // staging: row 0..31, quarter 0..7

    float acc[4][4];
#pragma unroll
    for (int a = 0; a < 4; a++)
#pragma unroll
        for (int c = 0; c < 4; c++) acc[a][c] = 0.f;

    for (int j0 = 0; j0 < HH; j0 += 32) {
#pragma unroll
        for (int p = 0; p < 2; p++) {
            int row = p * 32 + srow;
            float4 av = *(const float4*)(enc + (size_t)(i0 + row) * HH + j0 + sq * 4);
            float4 bv = *(const float4*)(W1 + (size_t)(k0 + row) * HH + j0 + sq * 4);
            As[sq * 4 + 0][row] = av.x; As[sq * 4 + 1][row] = av.y;
            As[sq * 4 + 2][row] = av.z; As[sq * 4 + 3][row] = av.w;
            Bs[sq * 4 + 0][row] = bv.x; Bs[sq * 4 + 1][row] = bv.y;
            Bs[sq * 4 + 2][row] = bv.z; Bs[sq * 4 + 3][row] = bv.w;
        }
        __syncthreads();
#pragma unroll
        for (int j = 0; j < 32; j++) {
            float4 a = *(const float4*)&As[j][tx * 4];
            float4 b = *(const float4*)&Bs[j][ty * 4];
            float ar[4] = {a.x, a.y, a.z, a.w};
            float br[4] = {b.x, b.y, b.z, b.w};
#pragma unroll
            for (int ai = 0; ai < 4; ai++)
#pragma unroll
                for (int bk = 0; bk < 4; bk++)
                    acc[ai][bk] += ar[ai] * br[bk];
        }
        __syncthreads();
    }
#pragma unroll
    for (int ai = 0; ai < 4; ai++) {
        float4 r = make_float4(acc[ai][0], acc[ai][1], acc[ai][2], acc[ai][3]);
        *(float4*)(W1e + (size_t)(i0 + tx * 4 + ai) * HH + k0 + ty * 4) = r;
    }
}

// GRU step. grid 256 blocks (2 k each), 512 threads: b=tid&127, grp=tid>>7
// grp = (jh<<1)|s : s picks k, jh picks j-half. Weights (12 rows) in LDS.
__global__ __launch_bounds__(512) void gru_kernel(
    const float* __restrict__ hT_cur, float* __restrict__ hT_next,
    const float* __restrict__ xT,
    const float* __restrict__ w_ih, const float* __restrict__ w_hh,
    const float* __restrict__ b_ih, const float* __restrict__ b_hh) {
    __shared__ float wl[12 * HH];          // [s][m][g][j]
    __shared__ float partial[2][2][128][6]; // [jh][s][b][g6]
    int tid = threadIdx.x;
    int k0 = blockIdx.x * 2;
    for (int u = tid; u < 12 * HH; u += 512) {
        int r = u >> 9, j = u & (HH - 1);
        int s = r / 6, rem = r % 6;
        int m = rem / 3, g = rem % 3;
        int row = g * HH + k0 + s;
        const float* src = m ? w_hh : w_ih;
        wl[u] = src[(size_t)row * HH + j];
    }
    __syncthreads();

    int b = tid & 127, grp = tid >> 7;
    int s = grp & 1, jh = grp >> 1;
    const float* wp = wl + s * 6 * HH;
    float ai0 = 0.f, ai1 = 0.f, ai2 = 0.f, ah0 = 0.f, ah1 = 0.f, ah2 = 0.f;
    int jbeg = jh * 256, jend = jbeg + 256;
#pragma unroll 8
    for (int j = jbeg; j < jend; j++) {
        float xv = xT[j * BB + b];
        float hv = hT_cur[j * BB + b];
        ai0 += xv * wp[j];
        ai1 += xv * wp[HH + j];
        ai2 += xv * wp[2 * HH + j];
        ah0 += hv * wp[3 * HH + j];
        ah1 += hv * wp[4 * HH + j];
        ah2 += hv * wp[5 * HH + j];
    }
    partial[jh][s][b][0] = ai0; partial[jh][s][b][1] = ai1;
    partial[jh][s][b][2] = ai2; partial[jh][s][b][3] = ah0;
    partial[jh][s][b][4] = ah1; partial[jh][s][b][5] = ah2;
    __syncthreads();

    if (tid < 256) {
        int ss = tid >> 7, bb = tid & 127;
        int k = k0 + ss;
        float ir = partial[0][ss][bb][0] + partial[1][ss][bb][0];
        float iz = partial[0][ss][bb][1] + partial[1][ss][bb][1];
        float in = partial[0][ss][bb][2] + partial[1][ss][bb][2];
        float hr = partial[0][ss][bb][3] + partial[1][ss][bb][3];
        float hz = partial[0][ss][bb][4] + partial[1][ss][bb][4];
        float hn = partial[0][ss][bb][5] + partial[1][ss][bb][5];
        float r = fast_sigmoid(ir + b_ih[k] + hr + b_hh[k]);
        float z = fast_sigmoid(iz + b_ih[HH + k] + hz + b_hh[HH + k]);
        float n = fast_tanh(in + b_ih[2 * HH + k] + r * (hn + b_hh[2 * HH + k]));
        float hold = hT_cur[k * BB + bb];
        hT_next[k * BB + bb] = (1.0f - z) * n + z * hold;
    }
}

// W2h[b*H + k] = dot(W2[k,:], h[:,b]) — same j-split structure, grid 256.
__global__ __launch_bounds__(512) void w2h_kernel(
    const float* __restrict__ hT, const float* __restrict__ W2,
    float* __restrict__ W2h) {
    __shared__ float wl[2 * HH];
    __shared__ float partial[2][2][128];
    int tid = threadIdx.x;
    int k0 = blockIdx.x * 2;
    for (int u = tid; u < 2 * HH; u += 512)
        wl[u] = W2[(size_t)(k0 + (u >> 9)) * HH + (u & (HH - 1))];
    __syncthreads();
    int b = tid & 127, grp = tid >> 7;
    int s = grp & 1, jh = grp >> 1;
    const float* wp = wl + s * HH;
    float acc = 0.f;
    int jbeg = jh * 256, jend = jbeg + 256;
#pragma unroll 8
    for (int j = jbeg; j < jend; j++)
        acc += hT[j * BB + b] * wp[j];
    partial[jh][s][b] = acc;
    __syncthreads();
    if (tid < 256) {
        int ss = tid >> 7, bb = tid & 127;
        W2h[bb * HH + k0 + ss] = partial[0][ss][bb] + partial[1][ss][bb];
    }
}

// one block per batch row b; 1024 threads
__global__ __launch_bounds__(1024) void attn_kernel(
    const float* __restrict__ W1e, const float* __restrict__ W2h,
    const float* __restrict__ v, int* __restrict__ mask,
    const float* __restrict__ enc, float* __restrict__ xT,
    float* __restrict__ out, int t) {
    __shared__ float w2l[HH];
    __shared__ float vl[HH];
    __shared__ float ul[NN];
    __shared__ float redv[16];
    __shared__ int redi[16];
    __shared__ float s_m, s_inv;
    __shared__ int s_idx;
    int b = blockIdx.x, tid = threadIdx.x;
    if (tid < HH) w2l[tid] = W2h[b * HH + tid];
    else vl[tid - HH] = v[tid - HH];
    __syncthreads();

    // u[b, n] = sum_k tanh(W1e[b,n,k] + W2h[b,k]) * v[k]
    int n = tid >> 2, q = tid & 3;
    const float* Wp = W1e + ((size_t)b * NN + n) * HH + q * 128;
    const float* w2p = w2l + q * 128;
    const float* vp = vl + q * 128;
    float part = 0.f;
#pragma unroll 4
    for (int jj = 0; jj < 128; jj += 4) {
        float4 wv = *(const float4*)(Wp + jj);
        part += fast_tanh(wv.x + w2p[jj]) * vp[jj];
        part += fast_tanh(wv.y + w2p[jj + 1]) * vp[jj + 1];
        part += fast_tanh(wv.z + w2p[jj + 2]) * vp[jj + 2];
        part += fast_tanh(wv.w + w2p[jj + 3]) * vp[jj + 3];
    }
    part += __shfl_xor(part, 1);
    part += __shfl_xor(part, 2);
    if (q == 0) ul[n] = part;
    __syncthreads();

    // masked value + first-index argmax
    float val = -3.0e38f;
    int bi = 1 << 30;
    if (tid < NN) {
        val = mask[b * NN + tid] ? -1.0e9f : ul[tid];
        bi = tid;
    }
    float bv = val;
    int wid = tid >> 6, lane = tid & 63;
    for (int off = 32; off > 0; off >>= 1) {
        float ov = __shfl_down(bv, off);
        int oi = __shfl_down(bi, off);
        if (ov > bv || (ov == bv && oi < bi)) { bv = ov; bi = oi; }
    }
    if (lane == 0) { redv[wid] = bv; redi[wid] = bi; }
    __syncthreads();
    if (tid == 0) {
        float m = redv[0]; int mi = redi[0];
        for (int w = 1; w < 16; w++) {
            if (redv[w] > m || (redv[w] == m && redi[w] < mi)) { m = redv[w]; mi = redi[w]; }
        }
        s_m = m; s_idx = mi;
    }
    __syncthreads();

    // softmax denominator
    float e = 0.f;
    if (tid < NN) e = expf(val - s_m);
    float sv = e;
    for (int off = 32; off > 0; off >>= 1) sv += __shfl_down(sv, off);
    if (lane == 0) redv[wid] = sv;
    __syncthreads();
    if (tid == 0) {
        float ssum = 0.f;
        for (int w = 0; w < 16; w++) ssum += redv[w];
        s_inv = 1.0f / ssum;
    }
    __syncthreads();

    // entropy
    float inv = s_inv;
    float term = 0.f;
    if (tid < NN) {
        float p = e * inv;
        term = p * logf(p + 1e-9f);
    }
    float tv = term;
    for (int off = 32; off > 0; off >>= 1) tv += __shfl_down(tv, off);
    if (lane == 0) redv[wid] = tv;
    __syncthreads();

    int idx = s_idx;
    if (tid == 0) {
        float ent = 0.f;
        for (int w = 0; w < 16; w++) ent += redv[w];
        out[b * T_STEPS + t] = (float)idx;
        out[BB * T_STEPS + b * T_STEPS + t] = logf(inv + 1e-9f);
        out[2 * BB * T_STEPS + b * T_STEPS + t] = -ent;
        mask[b * NN + idx] = 1;
    }
    __syncthreads();
    // gather prev_embed for next step into xT (transposed)
    if (tid < HH) xT[tid * BB + b] = enc[((size_t)b * NN + idx) * HH + tid];
}

extern "C" void kernel_launch(void* const* d_in, const int* in_sizes, int n_in,
                              void* d_out, int out_size, void* d_ws, size_t ws_size,
                              hipStream_t stream) {
    const float* enc  = (const float*)d_in[0];
    const float* w_ih = (const float*)d_in[1];
    const float* w_hh = (const float*)d_in[2];
    const float* b_ih = (const float*)d_in[3];
    const float* b_hh = (const float*)d_in[4];
    const float* W1   = (const float*)d_in[5];
    const float* W2   = (const float*)d_in[6];
    const float* v    = (const float*)d_in[7];
    float* out = (float*)d_out;

    float* ws = (float*)d_ws;
    float* W1e = ws;                          // 16777216 floats (64 MB)
    float* hT0 = W1e + (size_t)BB * NN * HH;  // 65536
    float* hT1 = hT0 + HH * BB;
    float* xT  = hT1 + HH * BB;
    float* W2h = xT + HH * BB;
    int*   mask = (int*)(W2h + HH * BB);

    init_kernel<<<64, 256, 0, stream>>>(hT0, xT, mask);
    w1e_gemm<<<dim3((BB * NN) / 64, HH / 64), 256, 0, stream>>>(enc, W1, W1e);

    for (int t = 0; t < T_STEPS; t++) {
        float* hc = (t & 1) ? hT1 : hT0;
        float* hn = (t & 1) ? hT0 : hT1;
        gru_kernel<<<HH / 2, 512, 0, stream>>>(hc, hn, xT, w_ih, w_hh, b_ih, b_hh);
        w2h_kernel<<<HH / 2, 512, 0, stream>>>(hn, W2, W2h);
        attn_kernel<<<BB, 1024, 0, stream>>>(W1e, W2h, v, mask, enc, xT, out, t);
    }
}